// Round 4
// baseline (328.879 us; speedup 1.0000x reference)
//
#include <hip/hip_runtime.h>

// Problem constants
#define IN_F   4096
#define OUT_F  4096
#define RK     32      // R_MIN
#define NB1    2048    // B1
#define MAXB   2048    // worst-case rows per bucket
#define LBATCH 10240   // B1 + B2*MULT
#define LRK    (LBATCH * RK)

typedef __attribute__((ext_vector_type(2))) __fp16 h2;
typedef __attribute__((ext_vector_type(8))) __fp16 h8;
typedef __attribute__((ext_vector_type(4))) float  f4;

// ws layout: cnt[64] | list[64*2048] (ints) | Rh[LRK] f16 | slabs[KS][LRK] f32

// ---------- binning: one block, LDS counters
__global__ __launch_bounds__(1024) void bin_rows(const int* __restrict__ wids,
                                                 int* __restrict__ cnt,
                                                 int* __restrict__ list) {
    __shared__ int lc[64];
    int t = threadIdx.x;
    if (t < 64) lc[t] = 0;
    __syncthreads();
    for (int it = t; it < 4096; it += 1024) {
        int b, v;
        if (it < NB1) { b = wids[it]; v = it; }
        else { int i = it - NB1; b = 32 + ((wids[NB1 + 4 * i] - 32) >> 2); v = i; }
        int p = atomicAdd(&lc[b], 1);
        list[b * MAXB + p] = v;
    }
    __syncthreads();
    if (t < 64) cnt[t] = lc[t];
}

// ---- s1 helpers: A staging (load coalesced f4 along cols; transpose to LDS [c][k])
__device__ __forceinline__ void lda(const float* __restrict__ As, int s,
                                    int kp0, int c40, f4 L[2][2]) {
    #pragma unroll
    for (int p = 0; p < 2; ++p) {
        const float* q = As + ((size_t)s * 32 + 2 * (kp0 + 8 * p)) * RK + c40;
        L[p][0] = *(const f4*)q;
        L[p][1] = *(const f4*)(q + RK);
    }
}
__device__ __forceinline__ void wra(__fp16 (*dst)[40], int kp0, int c40,
                                    const f4 L[2][2]) {
    #pragma unroll
    for (int p = 0; p < 2; ++p) {
        int k = 2 * (kp0 + 8 * p);
        #pragma unroll
        for (int j = 0; j < 4; ++j) {
            int c  = c40 + j;
            int kb = (k >> 3) ^ ((c >> 3) & 3);   // XOR k-octet swizzle (write conflicts)
            *(h2*)&dst[c][kb * 8 + (k & 7)] =
                __builtin_amdgcn_cvt_pkrtz(L[p][0][j], L[p][1][j]);
        }
    }
}

// ---------------- Stage 1: slab rows = X[16 x KCH] @ A[KCH x 32], MFMA f16.
// ONE WAVE per tile, NO barriers (per-wave LDS transpose buffer; DS is in-order
// per wave, compiler emits counted lgkmcnt). Part2 = 128 virtual single-adapter
// buckets (mm split), remapped so the 4 mm-buckets sharing X land on one XCD.
template<int KS>
__global__ __launch_bounds__(256, 3) void s1(const float* __restrict__ x,
                                             const float* __restrict__ A,
                                             const int* __restrict__ cnt,
                                             const int* __restrict__ list,
                                             float* __restrict__ slabs) {
    constexpr int KCH = IN_F / KS;   // k per chunk
    constexpr int NSC = KCH / 512;   // sub-chunks of 16 32-k steps
    __shared__ __fp16 At[4][2][32][40];
    int lane = threadIdx.x & 63, wv = threadIdx.x >> 6;
    int bx = blockIdx.x;                       // 0..159
    int p2 = bx >= 32;
    int u  = p2 ? ((bx - 32) & 31) : bx;       // group id
    int mm = p2 ? ((bx - 32) >> 5) : 0;        // adapter-within-group
    int vb  = p2 ? (32 + 4 * u + mm) : bx;     // adapter id
    int bkt = p2 ? (32 + u) : bx;              // list/cnt bucket
    int n = cnt[bkt];
    if (wv * 16 >= n) return;                  // wave-level exit, no barriers
    const int* lst = list + bkt * MAXB;
    int m = lane & 15, kg = lane >> 4;
    int kc = blockIdx.y;
    int k0 = kc * KCH;
    const float* Ab = A + ((size_t)vb * IN_F + k0) * RK;
    float* slab = slabs + (size_t)kc * LRK;
    int kp0 = lane >> 3;           // 0..7 (k-pair task; +8 for 2nd task)
    int c40 = (lane & 7) * 4;      // col base
    __fp16 (*buf)[32][40] = At[wv];

    for (int rt = wv; rt * 16 < n; rt += 4) {
        int it  = rt * 16 + m;
        int rid = lst[it < n ? it : n - 1];
        const float* xb = x + (size_t)(rid + (p2 ? NB1 : 0)) * IN_F + k0 + kg * 8;

        f4 acc0 = {0.f, 0.f, 0.f, 0.f}, acc1 = {0.f, 0.f, 0.f, 0.f};
        for (int sc = 0; sc < NSC; ++sc) {
            const float* xs = xb + sc * 512;
            const float* As = Ab + (size_t)sc * 512 * RK;
            // preload X fragments for all 16 steps (burst -> high MLP)
            h8 xf[16];
            #pragma unroll
            for (int s = 0; s < 16; ++s) {
                f4 x0 = *(const f4*)(xs + s * 32);
                f4 x1 = *(const f4*)(xs + s * 32 + 4);
                union { h8 v; h2 h[4]; } u2;
                u2.h[0] = __builtin_amdgcn_cvt_pkrtz(x0.x, x0.y);
                u2.h[1] = __builtin_amdgcn_cvt_pkrtz(x0.z, x0.w);
                u2.h[2] = __builtin_amdgcn_cvt_pkrtz(x1.x, x1.y);
                u2.h[3] = __builtin_amdgcn_cvt_pkrtz(x1.z, x1.w);
                xf[s] = u2.v;
            }
            // A pipeline: loads 2 steps ahead, LDS write 1 ahead, zero barriers
            f4 L0[2][2], L1[2][2];
            lda(As, 0, kp0, c40, L0);
            wra(buf[0], kp0, c40, L0);
            lda(As, 1, kp0, c40, L1);
            #pragma unroll
            for (int s = 0; s < 16; ++s) {
                h8 bf0, bf1;
                { int c = m;      int kb = kg ^ ((c >> 3) & 3); bf0 = *(const h8*)&buf[s & 1][c][kb * 8]; }
                { int c = 16 + m; int kb = kg ^ ((c >> 3) & 3); bf1 = *(const h8*)&buf[s & 1][c][kb * 8]; }
                if (s + 2 < 16) lda(As, s + 2, kp0, c40, (s & 1) ? L1 : L0);
                acc0 = __builtin_amdgcn_mfma_f32_16x16x32_f16(xf[s], bf0, acc0, 0, 0, 0);
                acc1 = __builtin_amdgcn_mfma_f32_16x16x32_f16(xf[s], bf1, acc1, 0, 0, 0);
                if (s + 1 < 16) wra(buf[(s + 1) & 1], kp0, c40, (s & 1) ? L0 : L1);
            }
        }
        // exact guarded stores (every slab element written exactly once)
        #pragma unroll
        for (int q = 0; q < 4; ++q) {
            int itq = rt * 16 + 4 * kg + q;
            if (itq < n) {
                int ridq = lst[itq];
                int srow = p2 ? (NB1 + 4 * ridq + mm) : ridq;
                float* sp = slab + (size_t)srow * RK + m;
                sp[0]  = acc0[q];
                sp[16] = acc1[q];
            }
        }
    }
}

// ---------------- slab reduction -> Rh f16 (RTN casts, matches ref's y rounding)
template<int KS>
__global__ __launch_bounds__(256) void reduceR(const float* __restrict__ slabs,
                                               __fp16* __restrict__ Rh) {
    int i = (blockIdx.x * 256 + threadIdx.x) * 8;
    f4 a = *(const f4*)(slabs + i);
    f4 b = *(const f4*)(slabs + i + 4);
    #pragma unroll
    for (int s = 1; s < KS; ++s) {
        a += *(const f4*)(slabs + (size_t)s * LRK + i);
        b += *(const f4*)(slabs + (size_t)s * LRK + i + 4);
    }
    h8 o;
    o[0] = (__fp16)a.x; o[1] = (__fp16)a.y; o[2] = (__fp16)a.z; o[3] = (__fp16)a.w;
    o[4] = (__fp16)b.x; o[5] = (__fp16)b.y; o[6] = (__fp16)b.z; o[7] = (__fp16)b.w;
    *(h8*)(Rh + i) = o;
}

// ---------------- Stage 2: out[rows x 32oc] = 2 * R @ B, one wave per (bucket,
// 32-col tile), rows looped inside. B fragments register-resident (loaded once),
// R fragments single 16B loads from L1-hot Rh. No LDS, no barriers.
__global__ __launch_bounds__(256, 4) void s2(const __fp16* __restrict__ Rh,
                                             const float* __restrict__ B,
                                             const int* __restrict__ cnt,
                                             const int* __restrict__ list,
                                             float* __restrict__ out) {
    int lane = threadIdx.x & 63, wv = threadIdx.x >> 6;
    int g   = blockIdx.x;              // 0..63 (p1 bucket / p2 group)
    int oct = blockIdx.y * 4 + wv;     // 0..127 (32-col tile)
    int p2  = g >= 32;
    int n = cnt[g];
    if (n == 0) return;
    const int* lst = list + g * MAXB;
    int m = lane & 15, kg = lane >> 4;
    int oc0 = oct * 32;
    int nkc = p2 ? 4 : 1;

    // B fragments: [kc][ct], loaded once per wave (strided scalar loads)
    h8 bf[4][2];
    #pragma unroll
    for (int kcb = 0; kcb < 4; ++kcb) {
        if (kcb < nkc) {
            int a = p2 ? (32 + 4 * (g - 32) + kcb) : g;
            const float* Bb = B + ((size_t)a * RK + kg * 8) * OUT_F + oc0 + m;
            #pragma unroll
            for (int ct = 0; ct < 2; ++ct) {
                union { h8 v; h2 h[4]; } u2;
                #pragma unroll
                for (int jj = 0; jj < 4; ++jj) {
                    float e0 = Bb[(size_t)(2 * jj) * OUT_F + ct * 16];
                    float e1 = Bb[(size_t)(2 * jj + 1) * OUT_F + ct * 16];
                    u2.h[jj] = __builtin_amdgcn_cvt_pkrtz(e0, e1);
                }
                bf[kcb][ct] = u2.v;
            }
        }
    }

    for (int rt = 0; rt * 16 < n; ++rt) {
        int it = rt * 16 + m;
        int ridm = lst[it < n ? it : n - 1];
        f4 acc0 = {0.f, 0.f, 0.f, 0.f}, acc1 = {0.f, 0.f, 0.f, 0.f};
        #pragma unroll
        for (int kcb = 0; kcb < 4; ++kcb) {
            if (kcb < nkc) {
                int rrow = p2 ? (NB1 + 4 * ridm + kcb) : ridm;
                h8 rf = *(const h8*)(Rh + (size_t)rrow * RK + kg * 8);
                acc0 = __builtin_amdgcn_mfma_f32_16x16x32_f16(rf, bf[kcb][0], acc0, 0, 0, 0);
                acc1 = __builtin_amdgcn_mfma_f32_16x16x32_f16(rf, bf[kcb][1], acc1, 0, 0, 0);
            }
        }
        #pragma unroll
        for (int q = 0; q < 4; ++q) {
            int itq = rt * 16 + 4 * kg + q;
            if (itq < n) {
                int ridq = lst[itq];
                int orow = p2 ? (NB1 + ridq) : ridq;
                float* op = out + (size_t)orow * OUT_F + oc0 + m;
                op[0]  = 2.f * acc0[q];
                op[16] = 2.f * acc1[q];
            }
        }
    }
}

extern "C" void kernel_launch(void* const* d_in, const int* in_sizes, int n_in,
                              void* d_out, int out_size, void* d_ws, size_t ws_size,
                              hipStream_t stream) {
    const float* x    = (const float*)d_in[0];
    const int*   wids = (const int*)  d_in[2];
    const float* A    = (const float*)d_in[3];
    const float* Bm   = (const float*)d_in[4];
    float* out = (float*)d_out;

    int* wsI  = (int*)d_ws;
    int* cnt  = wsI;
    int* list = wsI + 64;
    __fp16* Rh  = (__fp16*)(list + 64 * MAXB);
    float* slabs = (float*)((char*)Rh + (size_t)LRK * sizeof(__fp16));

    size_t fixed = (size_t)(64 + 64 * MAXB) * sizeof(int) + (size_t)LRK * sizeof(__fp16);
    int ks = (ws_size >= fixed + (size_t)8 * LRK * sizeof(float)) ? 8 : 4;

    bin_rows<<<dim3(1), dim3(1024), 0, stream>>>(wids, cnt, list);
    if (ks == 8) {
        s1<8><<<dim3(160, 8), dim3(256), 0, stream>>>(x, A, cnt, list, slabs);
        reduceR<8><<<dim3(LRK / 2048), dim3(256), 0, stream>>>(slabs, Rh);
    } else {
        s1<4><<<dim3(160, 4), dim3(256), 0, stream>>>(x, A, cnt, list, slabs);
        reduceR<4><<<dim3(LRK / 2048), dim3(256), 0, stream>>>(slabs, Rh);
    }
    s2<<<dim3(64, 32), dim3(256), 0, stream>>>(Rh, Bm, cnt, list, out);
}

// Round 5
// 305.835 us; speedup vs baseline: 1.0754x; 1.0754x over previous
//
#include <hip/hip_runtime.h>

// Problem constants
#define IN_F   4096
#define OUT_F  4096
#define RK     32      // R_MIN
#define NB1    2048    // B1
#define MAXB   2048    // worst-case rows per bucket
#define LBATCH 10240   // B1 + B2*MULT
#define LRK    (LBATCH * RK)

typedef __attribute__((ext_vector_type(2))) __fp16 h2;
typedef __attribute__((ext_vector_type(4))) __fp16 h4;
typedef __attribute__((ext_vector_type(8))) __fp16 h8;
typedef __attribute__((ext_vector_type(4))) float  f4;

// ws layout: cnt[64] | list[64*2048] (ints) | Rh[LRK] f16 | slabs[KS][LRK] f32

// ---------- binning: one block PER BUCKET, order-free compaction
__global__ __launch_bounds__(256) void bin_rows(const int* __restrict__ wids,
                                                int* __restrict__ cnt,
                                                int* __restrict__ list) {
    __shared__ int lc;
    int g = blockIdx.x, t = threadIdx.x;
    if (t == 0) lc = 0;
    __syncthreads();
    int* lg = list + g * MAXB;
    if (g < 32) {
        for (int i = t; i < NB1; i += 256)
            if (wids[i] == g) lg[atomicAdd(&lc, 1)] = i;
    } else {
        for (int i = t; i < 2048; i += 256)
            if (32 + ((wids[NB1 + 4 * i] - 32) >> 2) == g) lg[atomicAdd(&lc, 1)] = i;
    }
    __syncthreads();
    if (t == 0) cnt[g] = lc;
}

// ---- A staging helpers: one (32k x 32c) step per wave; coalesced f4 loads,
// packed-h2 transpose writes with XOR k-octet swizzle (round-4 verified).
__device__ __forceinline__ void lda(const float* __restrict__ As, int s,
                                    int kp0, int c40, f4 L[2][2]) {
    #pragma unroll
    for (int p = 0; p < 2; ++p) {
        const float* q = As + ((size_t)s * 32 + 2 * (kp0 + 8 * p)) * RK + c40;
        L[p][0] = *(const f4*)q;
        L[p][1] = *(const f4*)(q + RK);
    }
}
__device__ __forceinline__ void wra(__fp16 (*dst)[40], int kp0, int c40,
                                    const f4 L[2][2]) {
    #pragma unroll
    for (int p = 0; p < 2; ++p) {
        int k = 2 * (kp0 + 8 * p);
        #pragma unroll
        for (int j = 0; j < 4; ++j) {
            int c  = c40 + j;
            int kb = (k >> 3) ^ ((c >> 3) & 3);
            *(h2*)&dst[c][kb * 8 + (k & 7)] =
                __builtin_amdgcn_cvt_pkrtz(L[p][0][j], L[p][1][j]);
        }
    }
}

// per-wave inner loop: NST steps of 32k, 2-deep reg pipeline, ZERO barriers
template<int NST, int PITCH>
__device__ __forceinline__ void s1_waveloop(const float* __restrict__ Ap,
                                            const __fp16 (*Xl)[PITCH],
                                            __fp16 (*buf)[32][40], int koff0,
                                            int m, int kg, int kp0, int c40,
                                            f4& acc0, f4& acc1) {
    f4 L0[2][2], L1[2][2];
    lda(Ap, 0, kp0, c40, L0);
    wra(buf[0], kp0, c40, L0);
    if (NST > 1) lda(Ap, 1, kp0, c40, L1);
    #pragma unroll
    for (int s = 0; s < NST; ++s) {
        h8 xa = *(const h8*)&Xl[m][koff0 + s * 32 + kg * 8];
        int c0 = m,      kb0 = kg ^ ((c0 >> 3) & 3);
        int c1 = m + 16, kb1 = kg ^ ((c1 >> 3) & 3);
        h8 bf0 = *(const h8*)&buf[s & 1][c0][kb0 * 8];
        h8 bf1 = *(const h8*)&buf[s & 1][c1][kb1 * 8];
        if (s + 2 < NST) lda(Ap, s + 2, kp0, c40, ((s & 1) == 0) ? L0 : L1);
        acc0 = __builtin_amdgcn_mfma_f32_16x16x32_f16(xa, bf0, acc0, 0, 0, 0);
        acc1 = __builtin_amdgcn_mfma_f32_16x16x32_f16(xa, bf1, acc1, 0, 0, 0);
        if (s + 1 < NST) wra(buf[(s + 1) & 1], kp0, c40, ((s & 1) == 0) ? L1 : L0);
    }
}

// ---------------- Stage 1: block = (bucket, k-chunk, 16-row tile).
// X tile staged ONCE to LDS (f16). Then barrier-free per-wave pipelines:
// p1: 4 waves split k (LDS reduce at end); p2: 4 waves = 4 adapters.
template<int KS>
__global__ __launch_bounds__(256, 4) void s1(const float* __restrict__ x,
                                             const float* __restrict__ A,
                                             const int* __restrict__ cnt,
                                             const int* __restrict__ list,
                                             float* __restrict__ slabs) {
    constexpr int KCH   = IN_F / KS;     // 512 (KS=8)
    constexpr int PITCH = KCH + 8;
    constexpr int C4    = KCH / 4;
    __shared__ __fp16 Xl[16][PITCH];     // 16.6 KB (KS=8)
    __shared__ __fp16 At[4][2][32][40];  // 20.5 KB
    __shared__ int rowid[16];

    int t = threadIdx.x, lane = t & 63, wv = t >> 6;
    int m = lane & 15, kg = lane >> 4;
    int bx = blockIdx.x, kc = blockIdx.y, rt = blockIdx.z;
    int p2 = bx >= 32;
    int n = cnt[bx];
    if (rt * 16 >= n) return;
    const int* lst = list + bx * MAXB;
    if (t < 16) {
        int it = rt * 16 + t;
        rowid[t] = lst[it < n ? it : n - 1];
    }
    __syncthreads();

    // stage X tile (16 rows x KCH f32 -> f16), coalesced
    {
        int k0 = kc * KCH;
        #pragma unroll
        for (int itr = 0; itr < KCH / 64; ++itr) {
            int slot = t + 256 * itr;
            int row  = slot / C4;
            int c4   = slot & (C4 - 1);
            int xrow = rowid[row] + (p2 ? NB1 : 0);
            f4 v = *(const f4*)&x[(size_t)xrow * IN_F + k0 + 4 * c4];
            h4 pk;
            h2 a = __builtin_amdgcn_cvt_pkrtz(v.x, v.y);
            h2 b = __builtin_amdgcn_cvt_pkrtz(v.z, v.w);
            pk[0] = a.x; pk[1] = a.y; pk[2] = b.x; pk[3] = b.y;
            *(h4*)&Xl[row][4 * c4] = pk;
        }
    }
    __syncthreads();

    int kp0 = lane >> 3, c40 = (lane & 7) * 4;
    f4 acc0 = {0.f, 0.f, 0.f, 0.f}, acc1 = {0.f, 0.f, 0.f, 0.f};
    float* slab = slabs + (size_t)kc * LRK;

    if (p2) {
        int u = bx - 32;
        const float* Ap = A + ((size_t)(32 + 4 * u + wv) * IN_F + (size_t)kc * KCH) * RK;
        s1_waveloop<KCH / 32, PITCH>(Ap, Xl, At[wv], 0, m, kg, kp0, c40, acc0, acc1);
        #pragma unroll
        for (int q = 0; q < 4; ++q) {
            int itq = rt * 16 + 4 * kg + q;
            if (itq < n) {
                int rid = rowid[4 * kg + q];
                float* sp = slab + (size_t)(NB1 + 4 * rid + wv) * RK + m;
                sp[0]  = acc0[q];
                sp[16] = acc1[q];
            }
        }
    } else {
        const float* Ap = A + ((size_t)bx * IN_F + (size_t)kc * KCH + wv * (KCH / 4)) * RK;
        s1_waveloop<KCH / 128, PITCH>(Ap, Xl, At[wv], wv * (KCH / 4), m, kg, kp0, c40, acc0, acc1);
        // cross-wave reduce via LDS (reuse Xl region; X no longer needed)
        float* red = (float*)&Xl[0][0];
        __syncthreads();
        if (wv > 0) {
            *(f4*)&red[((wv - 1) * 64 + lane) * 8]     = acc0;
            *(f4*)&red[((wv - 1) * 64 + lane) * 8 + 4] = acc1;
        }
        __syncthreads();
        if (wv == 0) {
            #pragma unroll
            for (int j = 0; j < 3; ++j) {
                acc0 += *(const f4*)&red[(j * 64 + lane) * 8];
                acc1 += *(const f4*)&red[(j * 64 + lane) * 8 + 4];
            }
            #pragma unroll
            for (int q = 0; q < 4; ++q) {
                int itq = rt * 16 + 4 * kg + q;
                if (itq < n) {
                    int rid = rowid[4 * kg + q];
                    float* sp = slab + (size_t)rid * RK + m;
                    sp[0]  = acc0[q];
                    sp[16] = acc1[q];
                }
            }
        }
    }
}

// ---------------- slab reduction -> Rh f16 (RTN casts, matches ref's y rounding)
template<int KS>
__global__ __launch_bounds__(256) void reduceR(const float* __restrict__ slabs,
                                               __fp16* __restrict__ Rh) {
    int i = (blockIdx.x * 256 + threadIdx.x) * 8;
    f4 a = *(const f4*)(slabs + i);
    f4 b = *(const f4*)(slabs + i + 4);
    #pragma unroll
    for (int s = 1; s < KS; ++s) {
        a += *(const f4*)(slabs + (size_t)s * LRK + i);
        b += *(const f4*)(slabs + (size_t)s * LRK + i + 4);
    }
    h8 o;
    o[0] = (__fp16)a.x; o[1] = (__fp16)a.y; o[2] = (__fp16)a.z; o[3] = (__fp16)a.w;
    o[4] = (__fp16)b.x; o[5] = (__fp16)b.y; o[6] = (__fp16)b.z; o[7] = (__fp16)b.w;
    *(h8*)(Rh + i) = o;
}

// ---------------- Stage 2: out[rows x 32oc] = 2 * R @ B, one wave per (bucket,
// 32-col tile), rows looped inside. B fragments register-resident, R fragments
// single 16B loads from L2-hot Rh. No LDS, no barriers. (round-4 verified)
__global__ __launch_bounds__(256, 4) void s2(const __fp16* __restrict__ Rh,
                                             const float* __restrict__ B,
                                             const int* __restrict__ cnt,
                                             const int* __restrict__ list,
                                             float* __restrict__ out) {
    int lane = threadIdx.x & 63, wv = threadIdx.x >> 6;
    int g   = blockIdx.x;              // 0..63 (p1 bucket / p2 group)
    int oct = blockIdx.y * 4 + wv;     // 0..127 (32-col tile)
    int p2  = g >= 32;
    int n = cnt[g];
    if (n == 0) return;
    const int* lst = list + g * MAXB;
    int m = lane & 15, kg = lane >> 4;
    int oc0 = oct * 32;
    int nkc = p2 ? 4 : 1;

    h8 bf[4][2];
    #pragma unroll
    for (int kcb = 0; kcb < 4; ++kcb) {
        if (kcb < nkc) {
            int a = p2 ? (32 + 4 * (g - 32) + kcb) : g;
            const float* Bb = B + ((size_t)a * RK + kg * 8) * OUT_F + oc0 + m;
            #pragma unroll
            for (int ct = 0; ct < 2; ++ct) {
                union { h8 v; h2 h[4]; } u2;
                #pragma unroll
                for (int jj = 0; jj < 4; ++jj) {
                    float e0 = Bb[(size_t)(2 * jj) * OUT_F + ct * 16];
                    float e1 = Bb[(size_t)(2 * jj + 1) * OUT_F + ct * 16];
                    u2.h[jj] = __builtin_amdgcn_cvt_pkrtz(e0, e1);
                }
                bf[kcb][ct] = u2.v;
            }
        }
    }

    for (int rt = 0; rt * 16 < n; ++rt) {
        int it = rt * 16 + m;
        int ridm = lst[it < n ? it : n - 1];
        f4 acc0 = {0.f, 0.f, 0.f, 0.f}, acc1 = {0.f, 0.f, 0.f, 0.f};
        #pragma unroll
        for (int kcb = 0; kcb < 4; ++kcb) {
            if (kcb < nkc) {
                int rrow = p2 ? (NB1 + 4 * ridm + kcb) : ridm;
                h8 rf = *(const h8*)(Rh + (size_t)rrow * RK + kg * 8);
                acc0 = __builtin_amdgcn_mfma_f32_16x16x32_f16(rf, bf[kcb][0], acc0, 0, 0, 0);
                acc1 = __builtin_amdgcn_mfma_f32_16x16x32_f16(rf, bf[kcb][1], acc1, 0, 0, 0);
            }
        }
        #pragma unroll
        for (int q = 0; q < 4; ++q) {
            int itq = rt * 16 + 4 * kg + q;
            if (itq < n) {
                int ridq = lst[itq];
                int orow = p2 ? (NB1 + ridq) : ridq;
                float* op = out + (size_t)orow * OUT_F + oc0 + m;
                op[0]  = 2.f * acc0[q];
                op[16] = 2.f * acc1[q];
            }
        }
    }
}

extern "C" void kernel_launch(void* const* d_in, const int* in_sizes, int n_in,
                              void* d_out, int out_size, void* d_ws, size_t ws_size,
                              hipStream_t stream) {
    const float* x    = (const float*)d_in[0];
    const int*   wids = (const int*)  d_in[2];
    const float* A    = (const float*)d_in[3];
    const float* Bm   = (const float*)d_in[4];
    float* out = (float*)d_out;

    int* wsI  = (int*)d_ws;
    int* cnt  = wsI;
    int* list = wsI + 64;
    __fp16* Rh  = (__fp16*)(list + 64 * MAXB);
    float* slabs = (float*)((char*)Rh + (size_t)LRK * sizeof(__fp16));

    size_t fixed = (size_t)(64 + 64 * MAXB) * sizeof(int) + (size_t)LRK * sizeof(__fp16);
    int ks = (ws_size >= fixed + (size_t)8 * LRK * sizeof(float)) ? 8 : 4;

    bin_rows<<<dim3(64), dim3(256), 0, stream>>>(wids, cnt, list);
    if (ks == 8) {
        s1<8><<<dim3(64, 8, 8), dim3(256), 0, stream>>>(x, A, cnt, list, slabs);
        reduceR<8><<<dim3(160), dim3(256), 0, stream>>>(slabs, Rh);
    } else {
        s1<4><<<dim3(64, 4, 8), dim3(256), 0, stream>>>(x, A, cnt, list, slabs);
        reduceR<4><<<dim3(160), dim3(256), 0, stream>>>(slabs, Rh);
    }
    s2<<<dim3(64, 32), dim3(256), 0, stream>>>(Rh, Bm, cnt, list, out);
}